// Round 6
// baseline (251.366 us; speedup 1.0000x reference)
//
#include <hip/hip_runtime.h>
#include <hip/hip_bf16.h>
#include <stdint.h>

typedef __attribute__((ext_vector_type(8))) short bf16x8;
typedef __attribute__((ext_vector_type(4))) float f32x4;

#define DEVI static __device__ __forceinline__

// Problem sizes (fixed)
static constexpr int B_SZ = 4096, N_SZ = 128, H_SZ = 128, W_SZ = 64;

// ws layout (bytes), all 16B aligned
static constexpr size_t OFF_W1 = 0;                      // 128 * 128*128 bf16 = 4 MB (UNswizzled [n][c][h])
static constexpr size_t OFF_W2 = OFF_W1 + 4194304;       // 128 * 64*128 bf16 = 2 MB (UNswizzled [n][w][k])
static constexpr size_t OFF_F1 = OFF_W2 + 2097152;       // 128*128 bf16 = 32 KB (swizzled [o][h])
static constexpr size_t OFF_F2 = OFF_F1 + 32768;         // 384*128 bf16 = 96 KB (swizzled [o][j])
static constexpr size_t OFF_H  = OFF_F2 + 98304;         // 4096*128 bf16 = 1 MB (per-128-row tile, swizzled)

DEVI unsigned short f2bf(float f) {
  union { __hip_bfloat16 b; unsigned short u; } cv;
  cv.b = __float2bfloat16(f);
  return cv.u;
}
DEVI float bf2f(unsigned short u) {
  union { unsigned int i; float f; } cv;
  cv.i = ((unsigned int)u) << 16;
  return cv.f;
}

// Read one MFMA fragment (8 contiguous bf16 along k) from a swizzled LDS tile.
// Tile layout: row stride 256B; 16B slot s stored at (s ^ (row&7)).
DEVI bf16x8 frag_ld(const unsigned char* base, int row, int kslot) {
  return *reinterpret_cast<const bf16x8*>(base + row * 256 + (((kslot ^ (row & 7)) << 4)));
}
// Unswizzled fragment read (global memory, 256B rows).
DEVI bf16x8 gfrag_ld(const unsigned char* base, int row, int kslot) {
  return *reinterpret_cast<const bf16x8*>(base + row * 256 + (kslot << 4));
}

// Stage an nrows x 128 fp32 tile (row stride in elems) into swizzled bf16 LDS.
DEVI void stage_f32_tile(const float* src, int row_stride, unsigned char* dst, int tid, int nrows) {
  for (int t = tid; t < nrows * 16; t += 256) {
    int row = t >> 4, s = t & 15;
    const float* p = src + (size_t)row * row_stride + s * 8;
    union { unsigned short u[8]; uint4 v; } pk;
#pragma unroll
    for (int j = 0; j < 8; ++j) pk.u[j] = f2bf(p[j]);
    *reinterpret_cast<uint4*>(dst + row * 256 + ((s ^ (row & 7)) << 4)) = pk.v;
  }
}

// ---------------- prep: convert+transpose weights into ws (bf16) ----------------
__global__ __launch_bounds__(256) void prep_kernel(const float* __restrict__ rw1,
                                                   const float* __restrict__ rw2,
                                                   const float* __restrict__ fc1w,
                                                   const float* __restrict__ fc2w,
                                                   unsigned char* __restrict__ ws) {
  const int T_W1 = 128 * 128 * 16;  // (n,s,c): W1t[n][c][h=s*8+j] = rw1[n][h][c]  (c = output h)
  const int T_W2 = 128 * 64 * 16;   // (n,s,w): W2t[n][w][k=s*8+j] = rw2[n][k][w]
  const int T_F1 = 128 * 16;        // (o,s):   F1s[o][h]          = fc1w[o][h]  (swizzled)
  const int T_F2 = 384 * 16;
  int id = blockIdx.x * 256 + threadIdx.x;
  if (id < T_W1) {
    int c = id & 127, rest = id >> 7;
    int s = rest & 15, n = rest >> 4;
    const float* src = rw1 + (size_t)n * 16384 + (size_t)(s * 8) * 128 + c;
    union { unsigned short u[8]; uint4 v; } pk;
#pragma unroll
    for (int j = 0; j < 8; ++j) pk.u[j] = f2bf(src[(size_t)j * 128]);
    size_t dst = OFF_W1 + ((size_t)n * 128 + c) * 256 + (size_t)(s << 4);
    *reinterpret_cast<uint4*>(ws + dst) = pk.v;
    return;
  }
  id -= T_W1;
  if (id < T_W2) {
    int w = id & 63, rest = id >> 6;
    int s = rest & 15, n = rest >> 4;
    const float* src = rw2 + (size_t)n * 8192 + (size_t)(s * 8) * 64 + w;
    union { unsigned short u[8]; uint4 v; } pk;
#pragma unroll
    for (int j = 0; j < 8; ++j) pk.u[j] = f2bf(src[(size_t)j * 64]);
    size_t dst = OFF_W2 + ((size_t)n * 64 + w) * 256 + (size_t)(s << 4);
    *reinterpret_cast<uint4*>(ws + dst) = pk.v;
    return;
  }
  id -= T_W2;
  if (id < T_F1) {
    int s = id & 15, o = id >> 4;
    const float* src = fc1w + (size_t)o * 128 + s * 8;
    union { unsigned short u[8]; uint4 v; } pk;
#pragma unroll
    for (int j = 0; j < 8; ++j) pk.u[j] = f2bf(src[j]);
    *reinterpret_cast<uint4*>(ws + OFF_F1 + (size_t)o * 256 + ((s ^ (o & 7)) << 4)) = pk.v;
    return;
  }
  id -= T_F1;
  if (id < T_F2) {
    int s = id & 15, o = id >> 4;
    const float* src = fc2w + (size_t)o * 128 + s * 8;
    union { unsigned short u[8]; uint4 v; } pk;
#pragma unroll
    for (int j = 0; j < 8; ++j) pk.u[j] = f2bf(src[j]);
    *reinterpret_cast<uint4*>(ws + OFF_F2 + (size_t)o * 256 + ((s ^ (o & 7)) << 4)) = pk.v;
  }
}

// ---------------- recon v6: v4 structure @ 3 blocks/CU ----------------
// Block = (node n, 512 b-rows as 8x64 subtiles). W1 frags in VGPR (loaded once);
// W2 frags re-read per iter from L1/L2 (same addr -> cache-hot) to cut VGPR for
// occupancy 3 blocks/CU (48KB LDS). 2 barriers/iter:
//   G1 | [C] | epi1->sHN , wpref->bufn | [F] | G2 , epi2->global
// Hazards: G2(t) r:sHN vs epi1(t+1) w:sHN separated by [C](t+1);
//          wpref(t) w:bufn vs G1(t+1) r:bufn separated by [F](t).
// tmp output: bf16 [b][n][w] stashed in the upper half of each b's 32KB out3 slot.
__global__ __launch_bounds__(256, 3) void recon_kernel(const float* __restrict__ se,
                                                       const float* __restrict__ rb1,
                                                       const float* __restrict__ rb2,
                                                       const unsigned char* __restrict__ ws,
                                                       float* __restrict__ out3) {
  __shared__ unsigned char sSE[2][16384];  // SE 64-row tiles (swizzled rows b, 256B)
  __shared__ unsigned char sHN[16384];     // hn 64-row tile  (swizzled rows b, 256B)

  const int tid = threadIdx.x;
  const int n = blockIdx.x;    // 0..127 node
  const int btg = blockIdx.y;  // 0..7  -> 512 b-rows each
  const int b0 = btg * 512;

  const int wave = tid >> 6, lane = tid & 63;
  const int wm = wave >> 1, wq = wave & 1;  // wm: out-row half, wq: b half (32 each)
  const int lr = lane & 15, lk = lane >> 4;

  // W1 A-fragments (64 rows this wave-half): loop-invariant -> VGPRs (64 regs).
  const unsigned char* w1b = ws + OFF_W1 + (size_t)n * 32768;
  const unsigned char* w2b = ws + OFF_W2 + (size_t)n * 16384;
  bf16x8 w1f[4][4];
#pragma unroll
  for (int m = 0; m < 4; ++m)
#pragma unroll
    for (int kk = 0; kk < 4; ++kk)
      w1f[m][kk] = gfrag_ld(w1b, wm * 64 + m * 16 + lr, kk * 4 + lk);

  // biases (constant per lane across all tiles)
  float bias1[4][4], bias2[2][4];
#pragma unroll
  for (int m = 0; m < 4; ++m)
#pragma unroll
    for (int j = 0; j < 4; ++j) bias1[m][j] = rb1[(size_t)n * 128 + wm * 64 + m * 16 + lk * 4 + j];
#pragma unroll
  for (int m = 0; m < 2; ++m)
#pragma unroll
    for (int j = 0; j < 4; ++j) bias2[m][j] = rb2[(size_t)n * 64 + wm * 32 + m * 16 + lk * 4 + j];

  // stage SE subtile 0
  stage_f32_tile(se + ((size_t)b0 * 128 + n) * 128, 128 * 128, sSE[0], tid, 64);
  unsigned short* outus = reinterpret_cast<unsigned short*>(out3);
  __syncthreads();

  float4 fra[4], frb[4];  // next-tile staging registers

#pragma unroll 1
  for (int t = 0; t < 8; ++t) {
    unsigned char* bufc = sSE[t & 1];
    unsigned char* bufn = sSE[(t + 1) & 1];

    // issue next tile's global loads early (consumed after epi1 -> long latency cover)
    if (t < 7) {
      const float* sb = se + ((size_t)(b0 + (t + 1) * 64) * 128 + n) * 128;
#pragma unroll
      for (int k = 0; k < 4; ++k) {
        int c = tid + k * 256;
        int row = c >> 4, s = c & 15;
        const float* p = sb + (size_t)row * 16384 + s * 8;
        fra[k] = *reinterpret_cast<const float4*>(p);
        frb[k] = *reinterpret_cast<const float4*>(p + 4);
      }
    }

    // GEMM1': 128(h_out) x 64(b) x 128(k); wave owns 64 x 32
    f32x4 acc[4][2] = {};
    __builtin_amdgcn_s_setprio(1);
#pragma unroll
    for (int kk = 0; kk < 4; ++kk) {
      const int slot = kk * 4 + lk;
      bf16x8 bv[2];
#pragma unroll
      for (int q = 0; q < 2; ++q) bv[q] = frag_ld(bufc, wq * 32 + q * 16 + lr, slot);
#pragma unroll
      for (int m = 0; m < 4; ++m)
#pragma unroll
        for (int q = 0; q < 2; ++q)
          acc[m][q] = __builtin_amdgcn_mfma_f32_16x16x32_bf16(w1f[m][kk], bv[q], acc[m][q], 0, 0, 0);
    }
    __builtin_amdgcn_s_setprio(0);
    __syncthreads();  // [C] prev G2's sHN readers + this G1's bufc readers done

    // W2 A-fragments: re-read from L1/L2 (same address every iter -> cache-hot);
    // issued here, consumed after [F] in G2 -> latency hidden under epi1+wpref.
    bf16x8 w2f[2][4];
#pragma unroll
    for (int m = 0; m < 2; ++m)
#pragma unroll
      for (int kk = 0; kk < 4; ++kk)
        w2f[m][kk] = gfrag_ld(w2b, wm * 32 + m * 16 + lr, kk * 4 + lk);

    // epilogue1: hn[b][k] = relu(C1t[k][b] + rb1[k]) -> bf16 into sHN
    // lane: b = wq*32+q*16+lr, k = wm*64+m*16+lk*4+j  -> 8B write
#pragma unroll
    for (int m = 0; m < 4; ++m) {
      const int k0 = wm * 64 + m * 16 + lk * 4;
      const int s16 = k0 >> 3, half = (k0 >> 2) & 1;
#pragma unroll
      for (int q = 0; q < 2; ++q) {
        const int b = wq * 32 + q * 16 + lr;
        union { unsigned short u[4]; uint2 v; } pk;
#pragma unroll
        for (int j = 0; j < 4; ++j) {
          float v = acc[m][q][j] + bias1[m][j];
          v = v > 0.f ? v : 0.f;
          pk.u[j] = f2bf(v);
        }
        *reinterpret_cast<uint2*>(sHN + b * 256 + ((s16 ^ (b & 7)) << 4) + half * 8) = pk.v;
      }
    }

    // write prefetched SE(t+1) into the other SE buffer (fra/frb die here)
    if (t < 7) {
#pragma unroll
      for (int k = 0; k < 4; ++k) {
        int c = tid + k * 256;
        int row = c >> 4, s = c & 15;
        union { unsigned short u[8]; uint4 v; } pk;
#pragma unroll
        for (int j = 0; j < 4; ++j) pk.u[j] = f2bf(fra[k][j]);
#pragma unroll
        for (int j = 0; j < 4; ++j) pk.u[4 + j] = f2bf(frb[k][j]);
        *reinterpret_cast<uint4*>(bufn + row * 256 + ((s ^ (row & 7)) << 4)) = pk.v;
      }
    }
    __syncthreads();  // [F] sHN + bufn ready

    // GEMM2': 64(w) x 64(b) x 128(k); wave owns 32 x 32
    f32x4 acc2[2][2] = {};
    __builtin_amdgcn_s_setprio(1);
#pragma unroll
    for (int kk = 0; kk < 4; ++kk) {
      const int slot = kk * 4 + lk;
      bf16x8 bv[2];
#pragma unroll
      for (int q = 0; q < 2; ++q) bv[q] = frag_ld(sHN, wq * 32 + q * 16 + lr, slot);
#pragma unroll
      for (int m = 0; m < 2; ++m)
#pragma unroll
        for (int q = 0; q < 2; ++q)
          acc2[m][q] = __builtin_amdgcn_mfma_f32_16x16x32_bf16(w2f[m][kk], bv[q], acc2[m][q], 0, 0, 0);
    }
    __builtin_amdgcn_s_setprio(0);

    // epilogue2: tmp[b][n][w] bf16 at float-offset 4096 of b's out3 slot
    const int bt0 = b0 + t * 64;
#pragma unroll
    for (int m = 0; m < 2; ++m) {
      const int w0 = wm * 32 + m * 16 + lk * 4;
#pragma unroll
      for (int q = 0; q < 2; ++q) {
        const int b = bt0 + wq * 32 + q * 16 + lr;
        union { unsigned short u[4]; uint2 v; } pk;
#pragma unroll
        for (int j = 0; j < 4; ++j) pk.u[j] = f2bf(acc2[m][q][j] + bias2[m][j]);
        *reinterpret_cast<uint2*>(outus + (size_t)b * 16384 + 8192 + n * 64 + w0) = pk.v;
      }
    }
    // no closing barrier: G2(t) r:sHN vs epi1(t+1) w:sHN is separated by [C](t+1);
    // wpref(t) w:bufn vs G1(t+1) r:bufn by [F](t).
  }
}

// ---------------- transpose: tmp bf16 [b][n][w] -> out3 fp32 [b][w][n], LDS-free ----------------
__global__ __launch_bounds__(256) void transpose_kernel(float* __restrict__ out3) {
  const int b = blockIdx.x, wave = threadIdx.x >> 6, lane = threadIdx.x & 63;
  const unsigned short* t = reinterpret_cast<const unsigned short*>(out3) + (size_t)b * 16384 + 8192;
  float* dst = out3 + (size_t)b * 8192;
  uint4 r[2][2];
#pragma unroll
  for (int half = 0; half < 2; ++half) {
    const int g = half * 4 + wave;
    r[half][0] = *reinterpret_cast<const uint4*>(t + lane * 64 + g * 8);
    r[half][1] = *reinterpret_cast<const uint4*>(t + (size_t)(lane + 64) * 64 + g * 8);
  }
  __syncthreads();  // all reads done before dst writes clobber the tmp region
#pragma unroll
  for (int half = 0; half < 2; ++half) {
    const int g = half * 4 + wave;
    union { uint4 v; unsigned short u[8]; } p0, p1;
    p0.v = r[half][0];
    p1.v = r[half][1];
#pragma unroll
    for (int j = 0; j < 8; ++j) {
      dst[(g * 8 + j) * 128 + lane] = bf2f(p0.u[j]);
      dst[(g * 8 + j) * 128 + lane + 64] = bf2f(p1.u[j]);
    }
  }
}

// ---------------- forecast stage 1: h = relu(emb @ fc1^T + b1) -> ws (bf16, tile-swizzled) ----------------
__global__ __launch_bounds__(256) void f1_kernel(const float* __restrict__ emb,
                                                 const float* __restrict__ fc1b,
                                                 const unsigned char* __restrict__ ws,
                                                 unsigned char* __restrict__ hsw) {
  __shared__ unsigned char sA[32768];
  __shared__ unsigned char sB[32768];
  const int tid = threadIdx.x;
  const int bt = blockIdx.x;
  const int b0 = bt * 128;
  {
    const uint4* wp = reinterpret_cast<const uint4*>(ws + OFF_F1);
    uint4* d = reinterpret_cast<uint4*>(sB);
    for (int c = tid; c < 2048; c += 256) d[c] = wp[c];
  }
  stage_f32_tile(emb + (size_t)b0 * 128, 128, sA, tid, 128);
  __syncthreads();

  const int wave = tid >> 6, lane = tid & 63;
  const int wm = wave >> 1, wn = wave & 1;
  const int lr = lane & 15, lk = lane >> 4;

  f32x4 acc[4][4] = {};
#pragma unroll
  for (int kk = 0; kk < 4; ++kk) {
    bf16x8 af[4], bfv[4];
#pragma unroll
    for (int m = 0; m < 4; ++m) af[m] = frag_ld(sA, wm * 64 + m * 16 + lr, kk * 4 + lk);
#pragma unroll
    for (int q = 0; q < 4; ++q) bfv[q] = frag_ld(sB, wn * 64 + q * 16 + lr, kk * 4 + lk);
#pragma unroll
    for (int m = 0; m < 4; ++m)
#pragma unroll
      for (int q = 0; q < 4; ++q)
        acc[m][q] = __builtin_amdgcn_mfma_f32_16x16x32_bf16(af[m], bfv[q], acc[m][q], 0, 0, 0);
  }

  unsigned char* tile = hsw + (size_t)bt * 32768;
#pragma unroll
  for (int q = 0; q < 4; ++q) {
    int c = wn * 64 + q * 16 + lr;
    float bias = fc1b[c];
#pragma unroll
    for (int m = 0; m < 4; ++m) {
#pragma unroll
      for (int j = 0; j < 4; ++j) {
        int r = wm * 64 + m * 16 + lk * 4 + j;
        float v = acc[m][q][j] + bias;
        v = v > 0.f ? v : 0.f;
        *reinterpret_cast<unsigned short*>(tile + r * 256 + ((c * 2) ^ ((r & 7) << 4))) = f2bf(v);
      }
    }
  }
}

// ---------------- forecast stage 2: forecast = h @ fc2^T + b2 ----------------
__global__ __launch_bounds__(256) void f2_kernel(const unsigned char* __restrict__ hsw,
                                                 const unsigned char* __restrict__ f2s,
                                                 const float* __restrict__ fc2b,
                                                 float* __restrict__ out2) {
  __shared__ unsigned char sA[32768];
  __shared__ unsigned char sB[32768];
  const int tid = threadIdx.x;
  const int bt = blockIdx.x;      // 0..31
  const int ch = blockIdx.y;      // 0..2 (chunks of 128 output cols)
  const int b0 = bt * 128;
  {
    const uint4* ap = reinterpret_cast<const uint4*>(hsw + (size_t)bt * 32768);
    uint4* da = reinterpret_cast<uint4*>(sA);
    for (int c = tid; c < 2048; c += 256) da[c] = ap[c];
    const uint4* bp = reinterpret_cast<const uint4*>(f2s + (size_t)ch * 32768);
    uint4* db = reinterpret_cast<uint4*>(sB);
    for (int c = tid; c < 2048; c += 256) db[c] = bp[c];
  }
  __syncthreads();

  const int wave = tid >> 6, lane = tid & 63;
  const int wm = wave >> 1, wn = wave & 1;
  const int lr = lane & 15, lk = lane >> 4;

  f32x4 acc[4][4] = {};
#pragma unroll
  for (int kk = 0; kk < 4; ++kk) {
    bf16x8 af[4], bfv[4];
#pragma unroll
    for (int m = 0; m < 4; ++m) af[m] = frag_ld(sA, wm * 64 + m * 16 + lr, kk * 4 + lk);
#pragma unroll
    for (int q = 0; q < 4; ++q) bfv[q] = frag_ld(sB, wn * 64 + q * 16 + lr, kk * 4 + lk);
#pragma unroll
    for (int m = 0; m < 4; ++m)
#pragma unroll
      for (int q = 0; q < 4; ++q)
        acc[m][q] = __builtin_amdgcn_mfma_f32_16x16x32_bf16(af[m], bfv[q], acc[m][q], 0, 0, 0);
  }

#pragma unroll
  for (int q = 0; q < 4; ++q) {
    int o = ch * 128 + wn * 64 + q * 16 + lr;
    float bias = fc2b[o];
#pragma unroll
    for (int m = 0; m < 4; ++m) {
#pragma unroll
      for (int j = 0; j < 4; ++j) {
        int r = wm * 64 + m * 16 + lk * 4 + j;
        out2[(size_t)(b0 + r) * 384 + o] = acc[m][q][j] + bias;
      }
    }
  }
}

extern "C" void kernel_launch(void* const* d_in, const int* in_sizes, int n_in,
                              void* d_out, int out_size, void* d_ws, size_t ws_size,
                              hipStream_t stream) {
  const float* emb  = (const float*)d_in[0];
  const float* se   = (const float*)d_in[1];
  const float* slog = (const float*)d_in[2];
  const float* fc1w = (const float*)d_in[3];
  const float* fc1b = (const float*)d_in[4];
  const float* fc2w = (const float*)d_in[5];
  const float* fc2b = (const float*)d_in[6];
  const float* rw1  = (const float*)d_in[7];
  const float* rb1  = (const float*)d_in[8];
  const float* rw2  = (const float*)d_in[9];
  const float* rb2  = (const float*)d_in[10];
  float* out = (float*)d_out;
  unsigned char* ws = (unsigned char*)d_ws;

  // output 0: passthrough logits (B*N fp32)
  hipMemcpyAsync(out, slog, (size_t)B_SZ * N_SZ * sizeof(float),
                 hipMemcpyDeviceToDevice, stream);

  // weight prep (bf16 convert + transpose into ws)
  prep_kernel<<<1568, 256, 0, stream>>>(rw1, rw2, fc1w, fc2w, ws);

  // forecast head
  f1_kernel<<<32, 256, 0, stream>>>(emb, fc1b, ws, ws + OFF_H);
  f2_kernel<<<dim3(32, 3), 256, 0, stream>>>(ws + OFF_H, ws + OFF_F2, fc2b,
                                             out + (size_t)B_SZ * N_SZ);

  // reconstruction heads (dominant): 3-blocks/CU pipelined recon -> bf16 tmp -> transpose
  float* out3 = out + (size_t)B_SZ * N_SZ + (size_t)B_SZ * 384;
  recon_kernel<<<dim3(128, 8), 256, 0, stream>>>(se, rb1, rb2, ws, out3);
  transpose_kernel<<<4096, 256, 0, stream>>>(out3);
}

// Round 7
// 138.872 us; speedup vs baseline: 1.8101x; 1.8101x over previous
//
#include <hip/hip_runtime.h>
#include <hip/hip_bf16.h>
#include <stdint.h>

typedef __attribute__((ext_vector_type(8))) short bf16x8;
typedef __attribute__((ext_vector_type(4))) float f32x4;

#define DEVI static __device__ __forceinline__

// Problem sizes (fixed)
static constexpr int B_SZ = 4096, N_SZ = 128, H_SZ = 128, W_SZ = 64;

// ws layout (bytes), all 16B aligned
static constexpr size_t OFF_W1 = 0;                      // 128 * 128*128 bf16 = 4 MB (UNswizzled [n][c][h])
static constexpr size_t OFF_W2 = OFF_W1 + 4194304;       // 128 * 64*128 bf16 = 2 MB (UNswizzled [n][w][k])
static constexpr size_t OFF_F1 = OFF_W2 + 2097152;       // 128*128 bf16 = 32 KB (swizzled [o][h])
static constexpr size_t OFF_F2 = OFF_F1 + 32768;         // 384*128 bf16 = 96 KB (swizzled [o][j])
static constexpr size_t OFF_H  = OFF_F2 + 98304;         // 4096*128 bf16 = 1 MB (per-128-row tile, swizzled)

DEVI unsigned short f2bf(float f) {
  union { __hip_bfloat16 b; unsigned short u; } cv;
  cv.b = __float2bfloat16(f);
  return cv.u;
}
DEVI float bf2f(unsigned short u) {
  union { unsigned int i; float f; } cv;
  cv.i = ((unsigned int)u) << 16;
  return cv.f;
}

// Raw workgroup barrier: execution sync + LDS visibility (lgkmcnt), but does NOT
// drain vmcnt -> global prefetch loads stay in flight across it (v4's stall fix).
DEVI void bar_lds() {
  __builtin_amdgcn_sched_barrier(0);
  asm volatile("s_waitcnt lgkmcnt(0)" ::: "memory");
  __builtin_amdgcn_s_barrier();
  __builtin_amdgcn_sched_barrier(0);
}

// Read one MFMA fragment (8 contiguous bf16 along k) from a swizzled LDS tile.
// Tile layout: row stride 256B; 16B slot s stored at (s ^ (row&7)).
DEVI bf16x8 frag_ld(const unsigned char* base, int row, int kslot) {
  return *reinterpret_cast<const bf16x8*>(base + row * 256 + (((kslot ^ (row & 7)) << 4)));
}
// Unswizzled fragment read (global memory, 256B rows).
DEVI bf16x8 gfrag_ld(const unsigned char* base, int row, int kslot) {
  return *reinterpret_cast<const bf16x8*>(base + row * 256 + (kslot << 4));
}

// Stage an nrows x 128 fp32 tile (row stride in elems) into swizzled bf16 LDS.
DEVI void stage_f32_tile(const float* src, int row_stride, unsigned char* dst, int tid, int nrows) {
  for (int t = tid; t < nrows * 16; t += 256) {
    int row = t >> 4, s = t & 15;
    const float* p = src + (size_t)row * row_stride + s * 8;
    union { unsigned short u[8]; uint4 v; } pk;
#pragma unroll
    for (int j = 0; j < 8; ++j) pk.u[j] = f2bf(p[j]);
    *reinterpret_cast<uint4*>(dst + row * 256 + ((s ^ (row & 7)) << 4)) = pk.v;
  }
}

// ---------------- prep: convert+transpose weights into ws (bf16) ----------------
__global__ __launch_bounds__(256) void prep_kernel(const float* __restrict__ rw1,
                                                   const float* __restrict__ rw2,
                                                   const float* __restrict__ fc1w,
                                                   const float* __restrict__ fc2w,
                                                   unsigned char* __restrict__ ws) {
  const int T_W1 = 128 * 128 * 16;  // (n,s,c): W1t[n][c][h=s*8+j] = rw1[n][h][c]  (c = output h)
  const int T_W2 = 128 * 64 * 16;   // (n,s,w): W2t[n][w][k=s*8+j] = rw2[n][k][w]
  const int T_F1 = 128 * 16;        // (o,s):   F1s[o][h]          = fc1w[o][h]  (swizzled)
  const int T_F2 = 384 * 16;
  int id = blockIdx.x * 256 + threadIdx.x;
  if (id < T_W1) {
    int c = id & 127, rest = id >> 7;
    int s = rest & 15, n = rest >> 4;
    const float* src = rw1 + (size_t)n * 16384 + (size_t)(s * 8) * 128 + c;
    union { unsigned short u[8]; uint4 v; } pk;
#pragma unroll
    for (int j = 0; j < 8; ++j) pk.u[j] = f2bf(src[(size_t)j * 128]);
    size_t dst = OFF_W1 + ((size_t)n * 128 + c) * 256 + (size_t)(s << 4);
    *reinterpret_cast<uint4*>(ws + dst) = pk.v;
    return;
  }
  id -= T_W1;
  if (id < T_W2) {
    int w = id & 63, rest = id >> 6;
    int s = rest & 15, n = rest >> 4;
    const float* src = rw2 + (size_t)n * 8192 + (size_t)(s * 8) * 64 + w;
    union { unsigned short u[8]; uint4 v; } pk;
#pragma unroll
    for (int j = 0; j < 8; ++j) pk.u[j] = f2bf(src[(size_t)j * 64]);
    size_t dst = OFF_W2 + ((size_t)n * 64 + w) * 256 + (size_t)(s << 4);
    *reinterpret_cast<uint4*>(ws + dst) = pk.v;
    return;
  }
  id -= T_W2;
  if (id < T_F1) {
    int s = id & 15, o = id >> 4;
    const float* src = fc1w + (size_t)o * 128 + s * 8;
    union { unsigned short u[8]; uint4 v; } pk;
#pragma unroll
    for (int j = 0; j < 8; ++j) pk.u[j] = f2bf(src[j]);
    *reinterpret_cast<uint4*>(ws + OFF_F1 + (size_t)o * 256 + ((s ^ (o & 7)) << 4)) = pk.v;
    return;
  }
  id -= T_F1;
  if (id < T_F2) {
    int s = id & 15, o = id >> 4;
    const float* src = fc2w + (size_t)o * 128 + s * 8;
    union { unsigned short u[8]; uint4 v; } pk;
#pragma unroll
    for (int j = 0; j < 8; ++j) pk.u[j] = f2bf(src[j]);
    *reinterpret_cast<uint4*>(ws + OFF_F2 + (size_t)o * 256 + ((s ^ (o & 7)) << 4)) = pk.v;
  }
}

// ---------------- recon v7: v4 structure + non-draining barriers + late load issue ----------------
// Block = (node n, 512 b-rows as 8x64 subtiles). W1+W2 frags in VGPR (loaded once).
// Per iter: G1 | [C] | epi1->sHN, wpref->bufn, issue loads(t+2) | [F] | G2, epi2.
// Barriers are raw s_barrier + lgkmcnt(0) (no vmcnt drain) so the SE prefetch for
// tile t+2 stays in flight across [F](t)+[C](t+1) -> ~600+ cyc latency cover.
// Hazards: G2(t) r:sHN vs epi1(t+1) w:sHN separated by [C](t+1);
//          wpref(t) w:bufn vs G1(t+1) r:bufn separated by [F](t);
//          G1(t) r:bufc vs wpref(t+1) w:bufc separated by [C](t+1).
// tmp output: bf16 [b][n][w] stashed in the upper half of each b's 32KB out3 slot.
__global__ __launch_bounds__(256, 2) void recon_kernel(const float* __restrict__ se,
                                                       const float* __restrict__ rb1,
                                                       const float* __restrict__ rb2,
                                                       const unsigned char* __restrict__ ws,
                                                       float* __restrict__ out3) {
  __shared__ unsigned char sSE[2][16384];  // SE 64-row tiles (swizzled rows b, 256B)
  __shared__ unsigned char sHN[16384];     // hn 64-row tile  (swizzled rows b, 256B)

  const int tid = threadIdx.x;
  const int n = blockIdx.x;    // 0..127 node (linear id % 8 == n % 8 -> same-n blocks share XCD)
  const int btg = blockIdx.y;  // 0..7  -> 512 b-rows each
  const int b0 = btg * 512;

  const int wave = tid >> 6, lane = tid & 63;
  const int wm = wave >> 1, wq = wave & 1;  // wm: out-row half, wq: b half (32 each)
  const int lr = lane & 15, lk = lane >> 4;

  // A-fragments of W1 (64 rows this wave-half) and W2 (32 rows): loop-invariant -> VGPRs.
  const unsigned char* w1b = ws + OFF_W1 + (size_t)n * 32768;
  const unsigned char* w2b = ws + OFF_W2 + (size_t)n * 16384;
  bf16x8 w1f[4][4], w2f[2][4];
#pragma unroll
  for (int m = 0; m < 4; ++m)
#pragma unroll
    for (int kk = 0; kk < 4; ++kk)
      w1f[m][kk] = gfrag_ld(w1b, wm * 64 + m * 16 + lr, kk * 4 + lk);
#pragma unroll
  for (int m = 0; m < 2; ++m)
#pragma unroll
    for (int kk = 0; kk < 4; ++kk)
      w2f[m][kk] = gfrag_ld(w2b, wm * 32 + m * 16 + lr, kk * 4 + lk);

  // biases (constant per lane across all tiles)
  float bias1[4][4], bias2[2][4];
#pragma unroll
  for (int m = 0; m < 4; ++m)
#pragma unroll
    for (int j = 0; j < 4; ++j) bias1[m][j] = rb1[(size_t)n * 128 + wm * 64 + m * 16 + lk * 4 + j];
#pragma unroll
  for (int m = 0; m < 2; ++m)
#pragma unroll
    for (int j = 0; j < 4; ++j) bias2[m][j] = rb2[(size_t)n * 64 + wm * 32 + m * 16 + lk * 4 + j];

  // stage SE subtile 0 directly
  stage_f32_tile(se + ((size_t)b0 * 128 + n) * 128, 128 * 128, sSE[0], tid, 64);
  unsigned short* outus = reinterpret_cast<unsigned short*>(out3);

  float4 fra[4], frb[4];  // next-tile staging registers
  // prologue: issue loads for tile 1 (consumed at wpref(0))
  {
    const float* sb = se + ((size_t)(b0 + 64) * 128 + n) * 128;
#pragma unroll
    for (int k = 0; k < 4; ++k) {
      int c = tid + k * 256;
      int row = c >> 4, s = c & 15;
      const float* p = sb + (size_t)row * 16384 + s * 8;
      fra[k] = *reinterpret_cast<const float4*>(p);
      frb[k] = *reinterpret_cast<const float4*>(p + 4);
    }
  }
  __syncthreads();  // tile 0 staged (prologue: full drain is fine once)

#pragma unroll 1
  for (int t = 0; t < 8; ++t) {
    unsigned char* bufc = sSE[t & 1];
    unsigned char* bufn = sSE[(t + 1) & 1];

    // GEMM1': 128(h_out) x 64(b) x 128(k); wave owns 64 x 32
    f32x4 acc[4][2] = {};
#pragma unroll
    for (int kk = 0; kk < 4; ++kk) {
      const int slot = kk * 4 + lk;
      bf16x8 bv[2];
#pragma unroll
      for (int q = 0; q < 2; ++q) bv[q] = frag_ld(bufc, wq * 32 + q * 16 + lr, slot);
#pragma unroll
      for (int m = 0; m < 4; ++m)
#pragma unroll
        for (int q = 0; q < 2; ++q)
          acc[m][q] = __builtin_amdgcn_mfma_f32_16x16x32_bf16(w1f[m][kk], bv[q], acc[m][q], 0, 0, 0);
    }
    bar_lds();  // [C] prev G2's sHN readers + this G1's bufc readers done (no vmcnt drain)

    // epilogue1: hn[b][k] = relu(C1t[k][b] + rb1[k]) -> bf16 into sHN
    // lane: b = wq*32+q*16+lr, k = wm*64+m*16+lk*4+j  -> 8B write
#pragma unroll
    for (int m = 0; m < 4; ++m) {
      const int k0 = wm * 64 + m * 16 + lk * 4;
      const int s16 = k0 >> 3, half = (k0 >> 2) & 1;
#pragma unroll
      for (int q = 0; q < 2; ++q) {
        const int b = wq * 32 + q * 16 + lr;
        union { unsigned short u[4]; uint2 v; } pk;
#pragma unroll
        for (int j = 0; j < 4; ++j) {
          float v = acc[m][q][j] + bias1[m][j];
          v = v > 0.f ? v : 0.f;
          pk.u[j] = f2bf(v);
        }
        *reinterpret_cast<uint2*>(sHN + b * 256 + ((s16 ^ (b & 7)) << 4) + half * 8) = pk.v;
      }
    }

    // write prefetched SE(t+1) into the other SE buffer (fra/frb consumed here;
    // compiler emits a counted vmcnt wait right before first use)
    if (t < 7) {
#pragma unroll
      for (int k = 0; k < 4; ++k) {
        int c = tid + k * 256;
        int row = c >> 4, s = c & 15;
        union { unsigned short u[8]; uint4 v; } pk;
#pragma unroll
        for (int j = 0; j < 4; ++j) pk.u[j] = f2bf(fra[k][j]);
#pragma unroll
        for (int j = 0; j < 4; ++j) pk.u[4 + j] = f2bf(frb[k][j]);
        *reinterpret_cast<uint4*>(bufn + row * 256 + ((s ^ (row & 7)) << 4)) = pk.v;
      }
    }
    // issue loads for tile t+2 now that fra/frb are free: consumed at wpref(t+1),
    // crossing [F](t) and [C](t+1) without any vmcnt drain -> ~600+ cyc cover.
    if (t < 6) {
      const float* sb = se + ((size_t)(b0 + (t + 2) * 64) * 128 + n) * 128;
#pragma unroll
      for (int k = 0; k < 4; ++k) {
        int c = tid + k * 256;
        int row = c >> 4, s = c & 15;
        const float* p = sb + (size_t)row * 16384 + s * 8;
        fra[k] = *reinterpret_cast<const float4*>(p);
        frb[k] = *reinterpret_cast<const float4*>(p + 4);
      }
    }
    bar_lds();  // [F] sHN + bufn ready

    // GEMM2': 64(w) x 64(b) x 128(k); wave owns 32 x 32
    f32x4 acc2[2][2] = {};
#pragma unroll
    for (int kk = 0; kk < 4; ++kk) {
      const int slot = kk * 4 + lk;
      bf16x8 bv[2];
#pragma unroll
      for (int q = 0; q < 2; ++q) bv[q] = frag_ld(sHN, wq * 32 + q * 16 + lr, slot);
#pragma unroll
      for (int m = 0; m < 2; ++m)
#pragma unroll
        for (int q = 0; q < 2; ++q)
          acc2[m][q] = __builtin_amdgcn_mfma_f32_16x16x32_bf16(w2f[m][kk], bv[q], acc2[m][q], 0, 0, 0);
    }

    // epilogue2: tmp[b][n][w] bf16 at float-offset 4096 of b's out3 slot
    const int bt0 = b0 + t * 64;
#pragma unroll
    for (int m = 0; m < 2; ++m) {
      const int w0 = wm * 32 + m * 16 + lk * 4;
#pragma unroll
      for (int q = 0; q < 2; ++q) {
        const int b = bt0 + wq * 32 + q * 16 + lr;
        union { unsigned short u[4]; uint2 v; } pk;
#pragma unroll
        for (int j = 0; j < 4; ++j) pk.u[j] = f2bf(acc2[m][q][j] + bias2[m][j]);
        *reinterpret_cast<uint2*>(outus + (size_t)b * 16384 + 8192 + n * 64 + w0) = pk.v;
      }
    }
    // no closing barrier: hazards covered by [C](t+1) / [F](t) as documented above.
  }
}

// ---------------- transpose: tmp bf16 [b][n][w] -> out3 fp32 [b][w][n], LDS-free ----------------
__global__ __launch_bounds__(256) void transpose_kernel(float* __restrict__ out3) {
  const int b = blockIdx.x, wave = threadIdx.x >> 6, lane = threadIdx.x & 63;
  const unsigned short* t = reinterpret_cast<const unsigned short*>(out3) + (size_t)b * 16384 + 8192;
  float* dst = out3 + (size_t)b * 8192;
  uint4 r[2][2];
#pragma unroll
  for (int half = 0; half < 2; ++half) {
    const int g = half * 4 + wave;
    r[half][0] = *reinterpret_cast<const uint4*>(t + lane * 64 + g * 8);
    r[half][1] = *reinterpret_cast<const uint4*>(t + (size_t)(lane + 64) * 64 + g * 8);
  }
  __syncthreads();  // all reads done before dst writes clobber the tmp region
#pragma unroll
  for (int half = 0; half < 2; ++half) {
    const int g = half * 4 + wave;
    union { uint4 v; unsigned short u[8]; } p0, p1;
    p0.v = r[half][0];
    p1.v = r[half][1];
#pragma unroll
    for (int j = 0; j < 8; ++j) {
      dst[(g * 8 + j) * 128 + lane] = bf2f(p0.u[j]);
      dst[(g * 8 + j) * 128 + lane + 64] = bf2f(p1.u[j]);
    }
  }
}

// ---------------- forecast stage 1: h = relu(emb @ fc1^T + b1) -> ws (bf16, tile-swizzled) ----------------
__global__ __launch_bounds__(256) void f1_kernel(const float* __restrict__ emb,
                                                 const float* __restrict__ fc1b,
                                                 const unsigned char* __restrict__ ws,
                                                 unsigned char* __restrict__ hsw) {
  __shared__ unsigned char sA[32768];
  __shared__ unsigned char sB[32768];
  const int tid = threadIdx.x;
  const int bt = blockIdx.x;
  const int b0 = bt * 128;
  {
    const uint4* wp = reinterpret_cast<const uint4*>(ws + OFF_F1);
    uint4* d = reinterpret_cast<uint4*>(sB);
    for (int c = tid; c < 2048; c += 256) d[c] = wp[c];
  }
  stage_f32_tile(emb + (size_t)b0 * 128, 128, sA, tid, 128);
  __syncthreads();

  const int wave = tid >> 6, lane = tid & 63;
  const int wm = wave >> 1, wn = wave & 1;
  const int lr = lane & 15, lk = lane >> 4;

  f32x4 acc[4][4] = {};
#pragma unroll
  for (int kk = 0; kk < 4; ++kk) {
    bf16x8 af[4], bfv[4];
#pragma unroll
    for (int m = 0; m < 4; ++m) af[m] = frag_ld(sA, wm * 64 + m * 16 + lr, kk * 4 + lk);
#pragma unroll
    for (int q = 0; q < 4; ++q) bfv[q] = frag_ld(sB, wn * 64 + q * 16 + lr, kk * 4 + lk);
#pragma unroll
    for (int m = 0; m < 4; ++m)
#pragma unroll
      for (int q = 0; q < 4; ++q)
        acc[m][q] = __builtin_amdgcn_mfma_f32_16x16x32_bf16(af[m], bfv[q], acc[m][q], 0, 0, 0);
  }

  unsigned char* tile = hsw + (size_t)bt * 32768;
#pragma unroll
  for (int q = 0; q < 4; ++q) {
    int c = wn * 64 + q * 16 + lr;
    float bias = fc1b[c];
#pragma unroll
    for (int m = 0; m < 4; ++m) {
#pragma unroll
      for (int j = 0; j < 4; ++j) {
        int r = wm * 64 + m * 16 + lk * 4 + j;
        float v = acc[m][q][j] + bias;
        v = v > 0.f ? v : 0.f;
        *reinterpret_cast<unsigned short*>(tile + r * 256 + ((c * 2) ^ ((r & 7) << 4))) = f2bf(v);
      }
    }
  }
}

// ---------------- forecast stage 2: forecast = h @ fc2^T + b2 ----------------
__global__ __launch_bounds__(256) void f2_kernel(const unsigned char* __restrict__ hsw,
                                                 const unsigned char* __restrict__ f2s,
                                                 const float* __restrict__ fc2b,
                                                 float* __restrict__ out2) {
  __shared__ unsigned char sA[32768];
  __shared__ unsigned char sB[32768];
  const int tid = threadIdx.x;
  const int bt = blockIdx.x;      // 0..31
  const int ch = blockIdx.y;      // 0..2 (chunks of 128 output cols)
  const int b0 = bt * 128;
  {
    const uint4* ap = reinterpret_cast<const uint4*>(hsw + (size_t)bt * 32768);
    uint4* da = reinterpret_cast<uint4*>(sA);
    for (int c = tid; c < 2048; c += 256) da[c] = ap[c];
    const uint4* bp = reinterpret_cast<const uint4*>(f2s + (size_t)ch * 32768);
    uint4* db = reinterpret_cast<uint4*>(sB);
    for (int c = tid; c < 2048; c += 256) db[c] = bp[c];
  }
  __syncthreads();

  const int wave = tid >> 6, lane = tid & 63;
  const int wm = wave >> 1, wn = wave & 1;
  const int lr = lane & 15, lk = lane >> 4;

  f32x4 acc[4][4] = {};
#pragma unroll
  for (int kk = 0; kk < 4; ++kk) {
    bf16x8 af[4], bfv[4];
#pragma unroll
    for (int m = 0; m < 4; ++m) af[m] = frag_ld(sA, wm * 64 + m * 16 + lr, kk * 4 + lk);
#pragma unroll
    for (int q = 0; q < 4; ++q) bfv[q] = frag_ld(sB, wn * 64 + q * 16 + lr, kk * 4 + lk);
#pragma unroll
    for (int m = 0; m < 4; ++m)
#pragma unroll
      for (int q = 0; q < 4; ++q)
        acc[m][q] = __builtin_amdgcn_mfma_f32_16x16x32_bf16(af[m], bfv[q], acc[m][q], 0, 0, 0);
  }

#pragma unroll
  for (int q = 0; q < 4; ++q) {
    int o = ch * 128 + wn * 64 + q * 16 + lr;
    float bias = fc2b[o];
#pragma unroll
    for (int m = 0; m < 4; ++m) {
#pragma unroll
      for (int j = 0; j < 4; ++j) {
        int r = wm * 64 + m * 16 + lk * 4 + j;
        out2[(size_t)(b0 + r) * 384 + o] = acc[m][q][j] + bias;
      }
    }
  }
}

extern "C" void kernel_launch(void* const* d_in, const int* in_sizes, int n_in,
                              void* d_out, int out_size, void* d_ws, size_t ws_size,
                              hipStream_t stream) {
  const float* emb  = (const float*)d_in[0];
  const float* se   = (const float*)d_in[1];
  const float* slog = (const float*)d_in[2];
  const float* fc1w = (const float*)d_in[3];
  const float* fc1b = (const float*)d_in[4];
  const float* fc2w = (const float*)d_in[5];
  const float* fc2b = (const float*)d_in[6];
  const float* rw1  = (const float*)d_in[7];
  const float* rb1  = (const float*)d_in[8];
  const float* rw2  = (const float*)d_in[9];
  const float* rb2  = (const float*)d_in[10];
  float* out = (float*)d_out;
  unsigned char* ws = (unsigned char*)d_ws;

  // output 0: passthrough logits (B*N fp32)
  hipMemcpyAsync(out, slog, (size_t)B_SZ * N_SZ * sizeof(float),
                 hipMemcpyDeviceToDevice, stream);

  // weight prep (bf16 convert + transpose into ws)
  prep_kernel<<<1568, 256, 0, stream>>>(rw1, rw2, fc1w, fc2w, ws);

  // forecast head
  f1_kernel<<<32, 256, 0, stream>>>(emb, fc1b, ws, ws + OFF_H);
  f2_kernel<<<dim3(32, 3), 256, 0, stream>>>(ws + OFF_H, ws + OFF_F2, fc2b,
                                             out + (size_t)B_SZ * N_SZ);

  // reconstruction heads (dominant): async-pipelined recon -> bf16 tmp -> transpose
  float* out3 = out + (size_t)B_SZ * N_SZ + (size_t)B_SZ * 384;
  recon_kernel<<<dim3(128, 8), 256, 0, stream>>>(se, rb1, rb2, ws, out3);
  transpose_kernel<<<4096, 256, 0, stream>>>(out3);
}